// Round 4
// baseline (449.610 us; speedup 1.0000x reference)
//
#include <hip/hip_runtime.h>
#include <hip/hip_bf16.h>

typedef __attribute__((ext_vector_type(8))) short short8;
typedef __attribute__((ext_vector_type(4))) float f32x4;
typedef __attribute__((ext_vector_type(4))) unsigned u32x4;

// LDS layout (bytes) — 40960 total => 4 blocks/CU (160 KiB LDS):
//   hres [48][104] bf16 @ 0      (9984)
//   buf1 [48][104] bf16 @ 9984   (9984)   hln(32r) -> o -> h2
//   buf2 q[32][104]|k[32][104]|vT[96][40] @ 19968 (20992) -> f1[48][200]
#define LDS_BYTES 40960
#define SH   104
#define SU   52
#define KOFF 3328
#define VOFF 6656
#define F1S  200
#define F1SU 100

#if __has_builtin(__builtin_amdgcn_cvt_pk_bf16_f32)
typedef __attribute__((ext_vector_type(2))) __bf16 bf16x2;
__device__ __forceinline__ unsigned pk2bf(float a, float b){
  bf16x2 v = __builtin_amdgcn_cvt_pk_bf16_f32(a, b);
  return __builtin_bit_cast(unsigned, v);
}
__device__ __forceinline__ unsigned short f2bf(float x){
  bf16x2 v = __builtin_amdgcn_cvt_pk_bf16_f32(x, x);
  return (unsigned short)(__builtin_bit_cast(unsigned, v) & 0xFFFFu);
}
#else
__device__ __forceinline__ unsigned short f2bf(float x){
  unsigned u = __float_as_uint(x);
  u += 0x7FFFu + ((u >> 16) & 1u);
  return (unsigned short)(u >> 16);
}
__device__ __forceinline__ unsigned pk2bf(float a, float b){
  return (unsigned)f2bf(a) | ((unsigned)f2bf(b) << 16);
}
#endif

#if __has_builtin(__builtin_amdgcn_rcpf)
__device__ __forceinline__ float fast_rcp(float x){ return __builtin_amdgcn_rcpf(x); }
#else
__device__ __forceinline__ float fast_rcp(float x){ return 1.f/x; }
#endif
#if __has_builtin(__builtin_amdgcn_rsqf)
__device__ __forceinline__ float fast_rsq(float x){ return __builtin_amdgcn_rsqf(x); }
#else
__device__ __forceinline__ float fast_rsq(float x){ return rsqrtf(x); }
#endif
#if __has_builtin(__builtin_amdgcn_exp2f)
__device__ __forceinline__ float fast_ex2(float x){ return __builtin_amdgcn_exp2f(x); }
#else
__device__ __forceinline__ float fast_ex2(float x){ return exp2f(x); }
#endif

__device__ __forceinline__ float bflo(unsigned u){ return __uint_as_float(u << 16); }
__device__ __forceinline__ float bfhi(unsigned u){ return __uint_as_float(u & 0xFFFF0000u); }
__device__ __forceinline__ float bf1(unsigned short h){ return __uint_as_float(((unsigned)h) << 16); }

// ---------------- zero only the atomic-target stripes of out ----------------
__global__ void zero_stripes(float* __restrict__ out){
  int k = blockIdx.x;          // 0..341
  int b = blockIdx.y;          // 0..31
  int t = threadIdx.x;         // 0..191 : 8 tokens x 24 float4
  int tok = 24*k + (t / 24);
  f32x4 z = {0.f, 0.f, 0.f, 0.f};
  *(f32x4*)(out + ((size_t)b*8192 + tok)*96 + 4*(t % 24)) = z;
}

// ---------------- weight pre-pack: fp32 [K][N] -> bf16 MFMA fragments ----------------
__global__ void pack_weights(const float* __restrict__ qkv_w, const float* __restrict__ out_w,
                             const float* __restrict__ ffn_w1, const float* __restrict__ ffn_w2,
                             short8* __restrict__ wsv){
  int f = blockIdx.x, lane = threadIdx.x;
  const float* W; int N, nt, kf;
  if (f < 54)      { W = qkv_w;  N = 288; nt = f/3;        kf = f%3; }
  else if (f < 72) { int i=f-54;  W = out_w;  N = 96;  nt = i/3; kf = i%3; }
  else if (f < 108){ int i=f-72;  W = ffn_w1; N = 192; nt = i/3; kf = i%3; }
  else             { int i=f-108; W = ffn_w2; N = 96;  nt = i/6; kf = i%6; }
  int n = lane & 15, kq = lane >> 4;
  short8 v;
#pragma unroll
  for (int j = 0; j < 8; ++j){
    int k = kf*32 + kq*8 + j;
    v[j] = (short)f2bf(W[(size_t)k * N + nt*16 + n]);
  }
  wsv[f*64 + lane] = v;
}

// ---------------- fused block kernel ----------------
// 512 thr (8 waves). Latency-oriented schedule: per-phase, each wave owns tiles that
// share one row-block; A-fragments hoisted to registers ONCE (breaks the compiler's
// alias-forced per-tile ds_read chains); dual accumulator chains halve MFMA dep depth.
__global__ __launch_bounds__(512, 8)
void fused_block(const float* __restrict__ x,
                 const float* __restrict__ ln1_g, const float* __restrict__ ln1_b,
                 const float* __restrict__ qkv_b,
                 const float* __restrict__ out_b,
                 const float* __restrict__ ln2_g, const float* __restrict__ ln2_b,
                 const float* __restrict__ ffn_b1, const float* __restrict__ ffn_b2,
                 const float* __restrict__ pln_g, const float* __restrict__ pln_b,
                 const short8* __restrict__ wsv,
                 float* __restrict__ out)
{
  __shared__ __align__(16) char smem[LDS_BYTES];
  unsigned short* hres  = (unsigned short*)smem;
  unsigned*       hresU = (unsigned*)smem;
  unsigned short* buf1  = (unsigned short*)(smem + 9984);
  unsigned*       buf1U = (unsigned*)(smem + 9984);
  unsigned short* buf2  = (unsigned short*)(smem + 19968);
  unsigned*       buf2U = (unsigned*)(smem + 19968);

  const int tid  = threadIdx.x;
  const int wave = tid >> 6, lane = tid & 63;
  const int lm   = lane & 15, quad = lane >> 4;
  __builtin_assume(wave >= 0 && wave < 8);
  __builtin_assume(lm >= 0 && lm < 16);
  __builtin_assume(quad >= 0 && quad < 4);
  const int g = blockIdx.x, b = blockIdx.y;
  const int t0 = 24 * g;
  const size_t xbase = ((size_t)b * 8192 + t0) * 96;
  const short8* wl = wsv + lane;

  // ---------- LN1 over 32 unique tokens -> hln bf16 (buf1)
  {
    const int row = tid >> 4, j = tid & 15;
    const float* xr = x + xbase + (size_t)row*96 + 6*j;
    float v[6];
#pragma unroll
    for (int e = 0; e < 3; ++e){ float2 t = *(const float2*)(xr + 2*e); v[2*e]=t.x; v[2*e+1]=t.y; }
    float s = 0.f, q2 = 0.f;
#pragma unroll
    for (int e = 0; e < 6; ++e){ s += v[e]; q2 += v[e]*v[e]; }
#pragma unroll
    for (int m = 1; m < 16; m <<= 1){ s += __shfl_xor(s, m, 16); q2 += __shfl_xor(q2, m, 16); }
    float mean = s * (1.f/96.f);
    float rstd = fast_rsq(q2 * (1.f/96.f) - mean*mean + 1e-5f);
#pragma unroll
    for (int e = 0; e < 3; ++e){
      float2 gg = *(const float2*)(ln1_g + 6*j + 2*e);
      float2 bb = *(const float2*)(ln1_b + 6*j + 2*e);
      buf1U[row*SU + 3*j + e] = pk2bf((v[2*e]-mean)*rstd*gg.x+bb.x,
                                      (v[2*e+1]-mean)*rstd*gg.y+bb.y);
    }
  }
  __syncthreads();

  // ---------- QKV: M=32, N=288 (18 nt), K=96; A-frags hoisted per wave (fixed mt)
  {
    const int mt = wave & 1, p = wave >> 1;
    __builtin_assume(p >= 0 && p < 4);
    const unsigned short* arow = buf1 + (16*mt + lm)*SH + quad*8;
    short8 h0 = *(const short8*)(arow);
    short8 h1 = *(const short8*)(arow + 32);
    short8 h2 = *(const short8*)(arow + 64);
    auto qkv_tile = [&](int nt){
      if (nt < 12){
        f32x4 acc0 = *(const f32x4*)(qkv_b + nt*16 + quad*4);
        f32x4 acc1 = {0.f,0.f,0.f,0.f};
        acc0 = __builtin_amdgcn_mfma_f32_16x16x32_bf16(wl[(nt*3+0)*64], h0, acc0, 0, 0, 0);
        acc1 = __builtin_amdgcn_mfma_f32_16x16x32_bf16(wl[(nt*3+1)*64], h1, acc1, 0, 0, 0);
        acc0 = __builtin_amdgcn_mfma_f32_16x16x32_bf16(wl[(nt*3+2)*64], h2, acc0, 0, 0, 0);
        int row = 16*mt + lm;
        unsigned idx = (nt < 6)
          ? (unsigned)(row*SU + nt*8 + quad*2)
          : (unsigned)((KOFF>>1) + row*SU + (nt-6)*8 + quad*2);
        buf2U[idx]     = pk2bf(acc0[0]+acc1[0], acc0[1]+acc1[1]);
        buf2U[idx + 1] = pk2bf(acc0[2]+acc1[2], acc0[3]+acc1[3]);
      } else {
        int col = nt*16 + lm;
        float bias = qkv_b[col];
        f32x4 acc0 = {bias, bias, bias, bias};
        f32x4 acc1 = {0.f,0.f,0.f,0.f};
        acc0 = __builtin_amdgcn_mfma_f32_16x16x32_bf16(h0, wl[(nt*3+0)*64], acc0, 0, 0, 0);
        acc1 = __builtin_amdgcn_mfma_f32_16x16x32_bf16(h1, wl[(nt*3+1)*64], acc1, 0, 0, 0);
        acc0 = __builtin_amdgcn_mfma_f32_16x16x32_bf16(h2, wl[(nt*3+2)*64], acc0, 0, 0, 0);
        int d2 = col - 192;
        int w0 = (VOFF >> 1) + d2*20 + 8*mt + 2*quad;
        buf2U[w0]     = pk2bf(acc0[0]+acc1[0], acc0[1]+acc1[1]);
        buf2U[w0 + 1] = pk2bf(acc0[2]+acc1[2], acc0[3]+acc1[3]);
      }
    };
#pragma unroll
    for (int i = 0; i < 4; ++i) qkv_tile(p + 4*i);
    if (p < 2) qkv_tile(p + 16);
  }
  __syncthreads();

  // ---------- attention: 18 units (3 windows x 6 heads); ALL reads hoisted above writes
  {
    const short8 z8 = {0,0,0,0,0,0,0,0};
    short8 qa0=z8,ka0=z8,va0=z8, qa1=z8,ka1=z8,va1=z8, qa2=z8,ka2=z8,va2=z8;
    const int u0 = wave, u1 = wave + 8, u2 = wave + 16;
    const int w0_=u0/6, h0_=u0-6*(u0/6), w1_=u1/6, h1_=u1-6*(u1/6);
    const int w2_=u2/6, h2_=u2-6*(u2/6);
    if (quad < 2){
      qa0 = *(const short8*)(buf2 +        (8*w0_ + lm)*SH + h0_*16 + quad*8);
      ka0 = *(const short8*)(buf2 + KOFF + (8*w0_ + lm)*SH + h0_*16 + quad*8);
      va0 = *(const short8*)(buf2 + VOFF + (h0_*16 + lm)*40 + 8*w0_ + quad*8);
      qa1 = *(const short8*)(buf2 +        (8*w1_ + lm)*SH + h1_*16 + quad*8);
      ka1 = *(const short8*)(buf2 + KOFF + (8*w1_ + lm)*SH + h1_*16 + quad*8);
      va1 = *(const short8*)(buf2 + VOFF + (h1_*16 + lm)*40 + 8*w1_ + quad*8);
      if (wave < 2){
        qa2 = *(const short8*)(buf2 +        (8*w2_ + lm)*SH + h2_*16 + quad*8);
        ka2 = *(const short8*)(buf2 + KOFF + (8*w2_ + lm)*SH + h2_*16 + quad*8);
        va2 = *(const short8*)(buf2 + VOFF + (h2_*16 + lm)*40 + 8*w2_ + quad*8);
      }
    }
    auto attn_compute = [&](short8 qa, short8 ka, short8 va, int w, int h){
      f32x4 sc = {0.f,0.f,0.f,0.f};
      sc = __builtin_amdgcn_mfma_f32_16x16x32_bf16(ka, qa, sc, 0, 0, 0);
      float p4[4]; float sum = 0.f;
#pragma unroll
      for (int r = 0; r < 4; ++r){
        int k = quad*4 + r;
        float e = fast_ex2(sc[r]*0.36067376f);   // exp(s*0.25) = exp2(s*0.25*log2e)
        p4[r] = (k <= lm) ? e : 0.f;
        sum += p4[r];
      }
      sum += __shfl_xor(sum, 16);
      sum += __shfl_xor(sum, 32);
      float rs = fast_rcp(sum);
      int x0 = (int)pk2bf(p4[0]*rs, p4[1]*rs);
      int x1 = (int)pk2bf(p4[2]*rs, p4[3]*rs);
      int srcA = lm + ((quad & 1) << 5);
      int e0 = __shfl(x0, srcA),      e1 = __shfl(x1, srcA);
      int e2 = __shfl(x0, srcA + 16), e3 = __shfl(x1, srcA + 16);
      short8 pa = z8;
      if (quad < 2){
        u32x4 t = {(unsigned)e0, (unsigned)e1, (unsigned)e2, (unsigned)e3};
        pa = __builtin_bit_cast(short8, t);
      }
      f32x4 oc = {0.f,0.f,0.f,0.f};
      oc = __builtin_amdgcn_mfma_f32_16x16x32_bf16(va, pa, oc, 0, 0, 0); // O^T[d][q]
      unsigned ob = (w*16 + lm)*SU + h*8 + quad*2;
      buf1U[ob]     = pk2bf(oc[0], oc[1]);
      buf1U[ob + 1] = pk2bf(oc[2], oc[3]);
    };
    attn_compute(qa0, ka0, va0, w0_, h0_);
    attn_compute(qa1, ka1, va1, w1_, h1_);
    if (wave < 2) attn_compute(qa2, ka2, va2, w2_, h2_);
  }
  __syncthreads();

  // ---------- out-proj + residual: waves 0-5, wave owns (w = wave>>1, 3 nt); frags hoisted
  if (wave < 6){
    const int w = wave >> 1, ntb = (wave & 1)*3;
    const unsigned short* arow = buf1 + (w*16 + lm)*SH + quad*8;
    short8 a0 = *(const short8*)(arow);
    short8 a1 = *(const short8*)(arow + 32);
    short8 a2 = *(const short8*)(arow + 64);
    f32x4 xr[3];
#pragma unroll
    for (int i = 0; i < 3; ++i)
      xr[i] = *(const f32x4*)(x + xbase + (size_t)(8*w + lm)*96 + (ntb+i)*16 + quad*4);
#pragma unroll
    for (int i = 0; i < 3; ++i){
      int nt = ntb + i;
      f32x4 acc0 = *(const f32x4*)(out_b + nt*16 + quad*4);
      f32x4 acc1 = {0.f,0.f,0.f,0.f};
      acc0 = __builtin_amdgcn_mfma_f32_16x16x32_bf16(wl[(54 + nt*3 + 0)*64], a0, acc0, 0, 0, 0);
      acc1 = __builtin_amdgcn_mfma_f32_16x16x32_bf16(wl[(54 + nt*3 + 1)*64], a1, acc1, 0, 0, 0);
      acc0 = __builtin_amdgcn_mfma_f32_16x16x32_bf16(wl[(54 + nt*3 + 2)*64], a2, acc0, 0, 0, 0);
      unsigned idx = (w*16 + lm)*SU + nt*8 + quad*2;
      hresU[idx]     = pk2bf(acc0[0]+acc1[0]+xr[i][0], acc0[1]+acc1[1]+xr[i][1]);
      hresU[idx + 1] = pk2bf(acc0[2]+acc1[2]+xr[i][2], acc0[3]+acc1[3]+xr[i][3]);
    }
  }
  __syncthreads();

  // ---------- LN2: 48 rows -> h2 bf16 (buf1, o dead)
  {
    const int j = tid & 15;
#pragma unroll
    for (int p = 0; p < 2; ++p){
      int row = p*32 + (tid >> 4);
      if (row < 48){
        float v[6];
#pragma unroll
        for (int e = 0; e < 3; ++e){
          unsigned u = hresU[row*SU + 3*j + e];
          v[2*e] = bflo(u); v[2*e+1] = bfhi(u);
        }
        float s = 0.f, q2 = 0.f;
#pragma unroll
        for (int e = 0; e < 6; ++e){ s += v[e]; q2 += v[e]*v[e]; }
#pragma unroll
        for (int m = 1; m < 16; m <<= 1){ s += __shfl_xor(s, m, 16); q2 += __shfl_xor(q2, m, 16); }
        float mean = s * (1.f/96.f);
        float rstd = fast_rsq(q2 * (1.f/96.f) - mean*mean + 1e-5f);
#pragma unroll
        for (int e = 0; e < 3; ++e){
          float2 gg = *(const float2*)(ln2_g + 6*j + 2*e);
          float2 bb = *(const float2*)(ln2_b + 6*j + 2*e);
          buf1U[row*SU + 3*j + e] = pk2bf((v[2*e]-mean)*rstd*gg.x+bb.x,
                                          (v[2*e+1]-mean)*rstd*gg.y+bb.y);
        }
      }
    }
  }
  __syncthreads();

  // ---------- FFN1 + gelu: waves 0-5, wave owns (mt = wave>>1, 6 nt); frags hoisted
  if (wave < 6){
    const int mt = wave >> 1, ntb = (wave & 1)*6;
    const unsigned short* arow = buf1 + (mt*16 + lm)*SH + quad*8;
    short8 a0 = *(const short8*)(arow);
    short8 a1 = *(const short8*)(arow + 32);
    short8 a2 = *(const short8*)(arow + 64);
#pragma unroll
    for (int i = 0; i < 6; ++i){
      int nt = ntb + i;
      f32x4 acc0 = *(const f32x4*)(ffn_b1 + nt*16 + quad*4);
      f32x4 acc1 = {0.f,0.f,0.f,0.f};
      acc0 = __builtin_amdgcn_mfma_f32_16x16x32_bf16(wl[(72 + nt*3 + 0)*64], a0, acc0, 0, 0, 0);
      acc1 = __builtin_amdgcn_mfma_f32_16x16x32_bf16(wl[(72 + nt*3 + 1)*64], a1, acc1, 0, 0, 0);
      acc0 = __builtin_amdgcn_mfma_f32_16x16x32_bf16(wl[(72 + nt*3 + 2)*64], a2, acc0, 0, 0, 0);
      float gl[4];
#pragma unroll
      for (int r = 0; r < 4; ++r){
        float uu = acc0[r] + acc1[r];
        float z = -2.3022081f * (uu + 0.044715f * uu*uu*uu);   // -(2z)*log2e
        float e = fast_ex2(z);
        gl[r] = uu * fast_rcp(1.f + e);          // u * sigmoid(2z)
      }
      unsigned idx = (mt*16 + lm)*F1SU + nt*8 + quad*2;
      buf2U[idx]     = pk2bf(gl[0], gl[1]);
      buf2U[idx + 1] = pk2bf(gl[2], gl[3]);
    }
  }
  __syncthreads();

  // ---------- FFN2 + residual: waves 0-5, wave owns (mt = wave>>1, 3 nt); 6 frags hoisted
  if (wave < 6){
    const int mt = wave >> 1, ntb = (wave & 1)*3;
    const unsigned short* frow = buf2 + (mt*16 + lm)*F1S + quad*8;
    short8 f0 = *(const short8*)(frow);
    short8 f1 = *(const short8*)(frow + 32);
    short8 f2 = *(const short8*)(frow + 64);
    short8 f3 = *(const short8*)(frow + 96);
    short8 f4 = *(const short8*)(frow + 128);
    short8 f5 = *(const short8*)(frow + 160);
#pragma unroll
    for (int i = 0; i < 3; ++i){
      int nt = ntb + i;
      f32x4 acc0 = *(const f32x4*)(ffn_b2 + nt*16 + quad*4);
      f32x4 acc1 = {0.f,0.f,0.f,0.f};
      acc0 = __builtin_amdgcn_mfma_f32_16x16x32_bf16(wl[(108 + nt*6 + 0)*64], f0, acc0, 0, 0, 0);
      acc1 = __builtin_amdgcn_mfma_f32_16x16x32_bf16(wl[(108 + nt*6 + 1)*64], f1, acc1, 0, 0, 0);
      acc0 = __builtin_amdgcn_mfma_f32_16x16x32_bf16(wl[(108 + nt*6 + 2)*64], f2, acc0, 0, 0, 0);
      acc1 = __builtin_amdgcn_mfma_f32_16x16x32_bf16(wl[(108 + nt*6 + 3)*64], f3, acc1, 0, 0, 0);
      acc0 = __builtin_amdgcn_mfma_f32_16x16x32_bf16(wl[(108 + nt*6 + 4)*64], f4, acc0, 0, 0, 0);
      acc1 = __builtin_amdgcn_mfma_f32_16x16x32_bf16(wl[(108 + nt*6 + 5)*64], f5, acc1, 0, 0, 0);
      unsigned idx = (mt*16 + lm)*SU + nt*8 + quad*2;
      unsigned u0 = hresU[idx], u1 = hresU[idx + 1];
      hresU[idx]     = pk2bf(bflo(u0)+acc0[0]+acc1[0], bfhi(u0)+acc0[1]+acc1[1]);
      hresU[idx + 1] = pk2bf(bflo(u1)+acc0[2]+acc1[2], bfhi(u1)+acc0[3]+acc1[3]);
    }
  }
  __syncthreads();

  // ---------- merged post-LN + combine + store
  {
    const int i = tid >> 4, c0 = tid & 15;
    const int l = t0 + i;
    const size_t obase = ((size_t)b * 8192 + l) * 96;
    int rowA, rowB = -1;
    if (i < 8)       rowA = i;
    else if (i < 16){ rowA = i;            rowB = 16 + (i - 8); }
    else if (i < 24){ rowA = 16 + (i - 8); rowB = 32 + (i - 16); }
    else             rowA = 32 + (i - 16);

    float g6[6], b6[6];
#pragma unroll
    for (int e = 0; e < 6; ++e){ g6[e] = pln_g[c0 + 16*e]; b6[e] = pln_b[c0 + 16*e]; }

    float yA[6];
    {
      float v[6];
#pragma unroll
      for (int e = 0; e < 6; ++e) v[e] = bf1(hres[rowA*SH + c0 + 16*e]);
      float s = 0.f, q2 = 0.f;
#pragma unroll
      for (int e = 0; e < 6; ++e){ s += v[e]; q2 += v[e]*v[e]; }
#pragma unroll
      for (int m = 1; m < 16; m <<= 1){ s += __shfl_xor(s, m, 16); q2 += __shfl_xor(q2, m, 16); }
      float mean = s * (1.f/96.f);
      float rstd = fast_rsq(q2 * (1.f/96.f) - mean*mean + 1e-5f);
#pragma unroll
      for (int e = 0; e < 6; ++e) yA[e] = (v[e]-mean)*rstd*g6[e] + b6[e];
    }
    if (rowB >= 0){
      float yB[6];
      {
        float v[6];
#pragma unroll
        for (int e = 0; e < 6; ++e) v[e] = bf1(hres[rowB*SH + c0 + 16*e]);
        float s = 0.f, q2 = 0.f;
#pragma unroll
        for (int e = 0; e < 6; ++e){ s += v[e]; q2 += v[e]*v[e]; }
#pragma unroll
        for (int m = 1; m < 16; m <<= 1){ s += __shfl_xor(s, m, 16); q2 += __shfl_xor(q2, m, 16); }
        float mean = s * (1.f/96.f);
        float rstd = fast_rsq(q2 * (1.f/96.f) - mean*mean + 1e-5f);
#pragma unroll
        for (int e = 0; e < 6; ++e) yB[e] = (v[e]-mean)*rstd*g6[e] + b6[e];
      }
#pragma unroll
      for (int e = 0; e < 6; ++e)
        out[obase + c0 + 16*e] = 0.5f * (yA[e] + yB[e]);
    } else {
      float inv = (l < 8 || l >= 8184) ? 1.0f : 0.5f;
#pragma unroll
      for (int e = 0; e < 6; ++e)
        atomicAdd(&out[obase + c0 + 16*e], yA[e] * inv);
    }
  }
}

extern "C" void kernel_launch(void* const* d_in, const int* in_sizes, int n_in,
                              void* d_out, int out_size, void* d_ws, size_t ws_size,
                              hipStream_t stream) {
  const float* x      = (const float*)d_in[0];
  const float* ln1_g  = (const float*)d_in[1];
  const float* ln1_b  = (const float*)d_in[2];
  const float* qkv_w  = (const float*)d_in[3];
  const float* qkv_b  = (const float*)d_in[4];
  const float* out_w  = (const float*)d_in[5];
  const float* out_b  = (const float*)d_in[6];
  const float* ln2_g  = (const float*)d_in[7];
  const float* ln2_b  = (const float*)d_in[8];
  const float* ffn_w1 = (const float*)d_in[9];
  const float* ffn_b1 = (const float*)d_in[10];
  const float* ffn_w2 = (const float*)d_in[11];
  const float* ffn_b2 = (const float*)d_in[12];
  const float* pln_g  = (const float*)d_in[13];
  const float* pln_b  = (const float*)d_in[14];
  float* out = (float*)d_out;
  short8* wsv = (short8*)d_ws;

  zero_stripes<<<dim3(342, 32), 192, 0, stream>>>(out);
  pack_weights<<<144, 64, 0, stream>>>(qkv_w, out_w, ffn_w1, ffn_w2, wsv);
  fused_block<<<dim3(341, 32), 512, 0, stream>>>(
      x, ln1_g, ln1_b, qkv_b, out_b, ln2_g, ln2_b, ffn_b1, ffn_b2,
      pln_g, pln_b, (const short8*)wsv, out);
}